// Round 9
// baseline (734.080 us; speedup 1.0000x reference)
//
#include <hip/hip_runtime.h>
#include <cstdint>
#include <cstddef>

// Problem constants
#define NB    4
#define SEQ   4096
#define EDIM  1024
#define DHEAD 512
#define NTOK  (NB * SEQ)     // 16384
#define FQK   2048           // Q and K features only
#define FQKV  2560

typedef __bf16 bf16x8 __attribute__((ext_vector_type(8)));
typedef float  f32x4  __attribute__((ext_vector_type(4)));

#define WAITCNT(VM) asm volatile("s_waitcnt vmcnt(" #VM ") lgkmcnt(0)" ::: "memory")
#define LGKM0()     asm volatile("s_waitcnt lgkmcnt(0)" ::: "memory")
#define SCHED0()    __builtin_amdgcn_sched_barrier(0)   // rule #18: fence MFMA hoisting
#define BAR()       __builtin_amdgcn_s_barrier()
#define PRIO1()     __builtin_amdgcn_s_setprio(1)
#define PRIO0()     __builtin_amdgcn_s_setprio(0)

__device__ __forceinline__ unsigned short f2bf(float f) {
  union { float f; unsigned int u; } v; v.f = f;
  return (unsigned short)((v.u + 0x7fffu + ((v.u >> 16) & 1u)) >> 16);
}

// async global->LDS, 16B per lane; LDS dest wave-uniform base, lane i -> base+i*16.
__device__ __forceinline__ void gld_lds16(const void* g, void* l) {
  __builtin_amdgcn_global_load_lds(
      (const __attribute__((address_space(1))) unsigned int*)g,
      (__attribute__((address_space(3))) unsigned int*)l, 16, 0, 0);
}

// ---------------------------------------------------------------------------
// 2-phase dbuf GEMM-BT core for k_qk / k_v (round-7, verified): 128x128, BK=32.
// ---------------------------------------------------------------------------
template <class Epi>
__device__ __forceinline__ void gemm_bt_core(
    const unsigned short* __restrict__ A, const unsigned short* __restrict__ B,
    int K, int lda, int ldb, int m0, int n0, Epi epi) {
  __shared__ __align__(16) unsigned short As[2][128 * 32];
  __shared__ __align__(16) unsigned short Bs[2][128 * 32];
  const int t = threadIdx.x;
  const int w = t >> 6;
  const int lane = t & 63;
  const int wr = w >> 1, wc = w & 1;
  const int l15 = lane & 15, c16 = lane >> 4, x3 = l15 & 3;

  f32x4 acc[4][4];
#pragma unroll
  for (int i = 0; i < 4; ++i)
#pragma unroll
    for (int j = 0; j < 4; ++j) acc[i][j] = f32x4{0.f, 0.f, 0.f, 0.f};

  const int c0 = w * 128 + lane;
  const int c1 = w * 128 + 64 + lane;
  const int r0 = c0 >> 2, s0 = (c0 & 3) ^ (r0 & 3);
  const int r1 = c1 >> 2, s1 = (c1 & 3) ^ (r1 & 3);
  const int o0 = (w * 128) * 8;
  const int o1 = (w * 128 + 64) * 8;
  const unsigned short* gA0 = A + (size_t)(m0 + r0) * lda + s0 * 8;
  const unsigned short* gA1 = A + (size_t)(m0 + r1) * lda + s1 * 8;
  const unsigned short* gB0 = B + (size_t)(n0 + r0) * ldb + s0 * 8;
  const unsigned short* gB1 = B + (size_t)(n0 + r1) * ldb + s1 * 8;

  auto STAGE = [&](int buf, int kt) {
    gld_lds16(gA0 + kt, &As[buf][o0]);
    gld_lds16(gA1 + kt, &As[buf][o1]);
    gld_lds16(gB0 + kt, &Bs[buf][o0]);
    gld_lds16(gB1 + kt, &Bs[buf][o1]);
  };

  STAGE(0, 0);
  const int NT = K >> 5;
  for (int tt = 0; tt < NT; ++tt) {
    const int cb = tt & 1;
    if (tt + 1 < NT) { STAGE(cb ^ 1, (tt + 1) * 32); WAITCNT(4); }
    else             { WAITCNT(0); }
    BAR();
    PRIO1();
    bf16x8 af[4], bfr[4];
#pragma unroll
    for (int tm = 0; tm < 4; ++tm) {
      int r = wr * 64 + tm * 16 + l15;
      af[tm] = *(const bf16x8*)&As[cb][r * 32 + ((c16 ^ x3) * 8)];
    }
#pragma unroll
    for (int tn = 0; tn < 4; ++tn) {
      int r = wc * 64 + tn * 16 + l15;
      bfr[tn] = *(const bf16x8*)&Bs[cb][r * 32 + ((c16 ^ x3) * 8)];
    }
#pragma unroll
    for (int tm = 0; tm < 4; ++tm)
#pragma unroll
      for (int tn = 0; tn < 4; ++tn)
        acc[tm][tn] = __builtin_amdgcn_mfma_f32_16x16x32_bf16(
            af[tm], bfr[tn], acc[tm][tn], 0, 0, 0);
    PRIO0();
    BAR();
  }
  epi(acc, wr, wc, lane);
}

// ---------------------------------------------------------------------------
// Utility kernels
// ---------------------------------------------------------------------------
__global__ void k_cvt_x(const float* __restrict__ X, unsigned short* __restrict__ Xb) {
  int i = blockIdx.x * blockDim.x + threadIdx.x;
  float4 v = ((const float4*)X)[i];
  ushort4 o;
  o.x = f2bf(v.x); o.y = f2bf(v.y); o.z = f2bf(v.z); o.w = f2bf(v.w);
  ((ushort4*)Xb)[i] = o;
}

__global__ void k_pack_w(const float* __restrict__ Wq, const float* __restrict__ Wk,
                         const float* __restrict__ Wv, unsigned short* __restrict__ Wb) {
  int i = blockIdx.x * blockDim.x + threadIdx.x;
  int idx = i * 4;
  int f = idx >> 10, e = idx & 1023;
  const float* src = (f < 1024) ? (Wq + (size_t)f * 1024)
                   : (f < 2048) ? (Wk + (size_t)(f - 1024) * 1024)
                                : (Wv + (size_t)(f - 2048) * 1024);
  float4 v = *(const float4*)(src + e);
  ushort4 o;
  o.x = f2bf(v.x); o.y = f2bf(v.y); o.z = f2bf(v.z); o.w = f2bf(v.w);
  ((ushort4*)Wb)[i] = o;
}

__global__ void k_pack_b(const float* __restrict__ bq, const float* __restrict__ bk,
                         const float* __restrict__ bv, float* __restrict__ bc) {
  int f = blockIdx.x * blockDim.x + threadIdx.x;
  if (f < FQKV)
    bc[f] = (f < 1024) ? bq[f] : (f < 2048) ? bk[f - 1024] : bv[f - 2048];
}

__global__ void k_zero_f(float* __restrict__ p) {
  int i = blockIdx.x * blockDim.x + threadIdx.x;
  p[i] = 0.f;
}

// ---------------------------------------------------------------------------
// QK / V projection GEMMs (round-7, verified)
// ---------------------------------------------------------------------------
__global__ __launch_bounds__(256) void k_qk(const unsigned short* __restrict__ Xb,
                                            const unsigned short* __restrict__ Wb,
                                            const float* __restrict__ bc,
                                            unsigned short* __restrict__ QK) {
  const int m0 = blockIdx.y * 128, n0 = blockIdx.x * 128;
  gemm_bt_core(Xb, Wb, EDIM, EDIM, EDIM, m0, n0,
    [&](f32x4 (&acc)[4][4], int wr, int wc, int lane) {
#pragma unroll
      for (int tm = 0; tm < 4; ++tm)
#pragma unroll
        for (int tn = 0; tn < 4; ++tn) {
          int kc = n0 + wc * 64 + tn * 16 + (lane & 15);
          float bias = bc[kc];
#pragma unroll
          for (int i = 0; i < 4; ++i) {
            int q = m0 + wr * 64 + tm * 16 + (lane >> 4) * 4 + i;
            __bf16 h = (__bf16)(acc[tm][tn][i] + bias);
            QK[(size_t)q * FQK + kc] = *(const unsigned short*)&h;
          }
        }
    });
}

__global__ __launch_bounds__(256) void k_v(const unsigned short* __restrict__ Xb,
                                           const unsigned short* __restrict__ Wb,
                                           const float* __restrict__ bc,
                                           unsigned short* __restrict__ Vt) {
  const int b = blockIdx.z;
  const int m0 = blockIdx.y * 128;  // d tile
  const int n0 = blockIdx.x * 128;  // s tile
  const unsigned short* A = Wb + (size_t)2048 * EDIM;
  const unsigned short* B = Xb + (size_t)b * SEQ * EDIM;
  unsigned short* Vb = Vt + (size_t)b * DHEAD * SEQ;
  gemm_bt_core(A, B, EDIM, EDIM, EDIM, m0, n0,
    [&](f32x4 (&acc)[4][4], int wr, int wc, int lane) {
#pragma unroll
      for (int tm = 0; tm < 4; ++tm)
#pragma unroll
        for (int tn = 0; tn < 4; ++tn) {
          int s = n0 + wc * 64 + tn * 16 + (lane & 15);
#pragma unroll
          for (int i = 0; i < 4; ++i) {
            int d = m0 + wr * 64 + tm * 16 + (lane >> 4) * 4 + i;
            __bf16 h = (__bf16)(acc[tm][tn][i] + bc[2048 + d]);
            Vb[(size_t)d * SEQ + s] = *(const unsigned short*)&h;
          }
        }
    });
}

// ---------------------------------------------------------------------------
// Scores, 8-phase (m201 template): 256q x 256k, BK=64, 8 waves (2M x 4N,
// per-wave 128x64), 128 KB LDS, conflict-free 8-slot swizzle (r4: cnt=0).
// Per K-tile, 4 quadrant phases: {ds_read subtile [stage in P0] -> BAR ->
// lgkmcnt(0)+sched_barrier(0) -> setprio(1) + 16 MFMA + setprio(0) -> BAR}.
// vmcnt(0) only at the K-tile boundary (loads ~3 phases old => ~free).
// ---------------------------------------------------------------------------
__global__ __launch_bounds__(512, 2) void k_scores8(const unsigned short* __restrict__ QK,
                                                    unsigned short* __restrict__ E_c,
                                                    float* __restrict__ ls, int b0) {
  __shared__ __align__(16) unsigned short LA[2][256 * 64];   // 2 x 32 KB
  __shared__ __align__(16) unsigned short LB[2][256 * 64];   // 2 x 32 KB
  const int z = blockIdx.z, rb = z >> 1, which = z & 1, b = b0 + rb;
  const int m0 = blockIdx.y * 256, n0 = blockIdx.x * 256;
  const unsigned short* Aq = QK + (size_t)b * SEQ * FQK + which * 512;
  const unsigned short* Bk = Aq + 1024;
  unsigned short* Eb = E_c + (size_t)z * SEQ * SEQ;
  float* lr = ls + (size_t)which * NTOK + (size_t)b * SEQ;
  const int t = threadIdx.x, w = t >> 6, lane = t & 63;
  const int wr = w >> 2, wc = w & 3;           // wave: 128q x 64k
  const int l15 = lane & 15, c16 = lane >> 4, x7 = l15 & 7;

  f32x4 acc[8][4];
#pragma unroll
  for (int i = 0; i < 8; ++i)
#pragma unroll
    for (int j = 0; j < 4; ++j) acc[i][j] = f32x4{0.f, 0.f, 0.f, 0.f};

  unsigned goffA[4], goffB[4]; int loff[4];
#pragma unroll
  for (int i = 0; i < 4; ++i) {
    int c = w * 64 + lane + 512 * i;
    int r = c >> 3;
    int sg = (c & 7) ^ (r & 7);
    goffA[i] = (unsigned)((m0 + r) * FQK + sg * 8);
    goffB[i] = (unsigned)((n0 + r) * FQK + sg * 8);
    loff[i] = (w * 64 + 512 * i) * 8;
  }

  auto STAGE = [&](int buf, int kh) {
#pragma unroll
    for (int i = 0; i < 4; ++i) gld_lds16(Aq + goffA[i] + kh, &LA[buf][loff[i]]);
#pragma unroll
    for (int i = 0; i < 4; ++i) gld_lds16(Bk + goffB[i] + kh, &LB[buf][loff[i]]);
  };

#define LDA_S(CB, R, KS) (*(const bf16x8*)&LA[CB][(R) * 64 + ((((KS) * 4 + c16) ^ x7) * 8)])
#define LDB_S(CB, R, KS) (*(const bf16x8*)&LB[CB][(R) * 64 + ((((KS) * 4 + c16) ^ x7) * 8)])

  STAGE(0, 0);
  WAITCNT(0);
  BAR();

  for (int kt = 0; kt < 8; ++kt) {            // K = 512 = 8 x 64
    const int cb = kt & 1;
    bf16x8 af[4][2], b0f[2][2], b1f[2][2];
    // ---- P0: stage next K-tile; read af-lo + bfr-lo; MFMA Q(m-lo, n-lo)
    if (kt < 7) STAGE(cb ^ 1, (kt + 1) * 64);
#pragma unroll
    for (int tq = 0; tq < 4; ++tq)
#pragma unroll
      for (int ks = 0; ks < 2; ++ks)
        af[tq][ks] = LDA_S(cb, wr * 128 + tq * 16 + l15, ks);
#pragma unroll
    for (int tn = 0; tn < 2; ++tn)
#pragma unroll
      for (int ks = 0; ks < 2; ++ks)
        b0f[tn][ks] = LDB_S(cb, wc * 64 + tn * 16 + l15, ks);
    BAR(); LGKM0(); SCHED0();
    PRIO1();
#pragma unroll
    for (int tq = 0; tq < 4; ++tq)
#pragma unroll
      for (int tn = 0; tn < 2; ++tn)
#pragma unroll
        for (int ks = 0; ks < 2; ++ks)
          acc[tq][tn] = __builtin_amdgcn_mfma_f32_16x16x32_bf16(
              af[tq][ks], b0f[tn][ks], acc[tq][tn], 0, 0, 0);
    PRIO0();
    BAR();
    // ---- P1: read bfr-hi; MFMA Q(m-lo, n-hi)
#pragma unroll
    for (int tn = 0; tn < 2; ++tn)
#pragma unroll
      for (int ks = 0; ks < 2; ++ks)
        b1f[tn][ks] = LDB_S(cb, wc * 64 + (tn + 2) * 16 + l15, ks);
    BAR(); LGKM0(); SCHED0();
    PRIO1();
#pragma unroll
    for (int tq = 0; tq < 4; ++tq)
#pragma unroll
      for (int tn = 0; tn < 2; ++tn)
#pragma unroll
        for (int ks = 0; ks < 2; ++ks)
          acc[tq][tn + 2] = __builtin_amdgcn_mfma_f32_16x16x32_bf16(
              af[tq][ks], b1f[tn][ks], acc[tq][tn + 2], 0, 0, 0);
    PRIO0();
    BAR();
    // ---- P2: read af-hi; MFMA Q(m-hi, n-hi)
#pragma unroll
    for (int tq = 0; tq < 4; ++tq)
#pragma unroll
      for (int ks = 0; ks < 2; ++ks)
        af[tq][ks] = LDA_S(cb, wr * 128 + 64 + tq * 16 + l15, ks);
    BAR(); LGKM0(); SCHED0();
    PRIO1();
#pragma unroll
    for (int tq = 0; tq < 4; ++tq)
#pragma unroll
      for (int tn = 0; tn < 2; ++tn)
#pragma unroll
        for (int ks = 0; ks < 2; ++ks)
          acc[4 + tq][tn + 2] = __builtin_amdgcn_mfma_f32_16x16x32_bf16(
              af[tq][ks], b1f[tn][ks], acc[4 + tq][tn + 2], 0, 0, 0);
    PRIO0();
    BAR();
    // ---- P3: reuse af-hi + bfr-lo; MFMA Q(m-hi, n-lo); K-tile boundary drain
    PRIO1();
#pragma unroll
    for (int tq = 0; tq < 4; ++tq)
#pragma unroll
      for (int tn = 0; tn < 2; ++tn)
#pragma unroll
        for (int ks = 0; ks < 2; ++ks)
          acc[4 + tq][tn] = __builtin_amdgcn_mfma_f32_16x16x32_bf16(
              af[tq][ks], b0f[tn][ks], acc[4 + tq][tn], 0, 0, 0);
    PRIO0();
    if (kt < 7) WAITCNT(0);
    BAR();
  }
#undef LDA_S
#undef LDB_S

  // Epilogue: exp + native bf16 cast + direct stores + row sums.
  const float scale = 0.04419417382415922f;  // 1/sqrt(512)
  float rs[8][4];
#pragma unroll
  for (int tm = 0; tm < 8; ++tm)
#pragma unroll
    for (int i = 0; i < 4; ++i) rs[tm][i] = 0.f;
#pragma unroll
  for (int tm = 0; tm < 8; ++tm)
#pragma unroll
    for (int tn = 0; tn < 4; ++tn) {
      int k = n0 + wc * 64 + tn * 16 + l15;
#pragma unroll
      for (int i = 0; i < 4; ++i) {
        int q = m0 + wr * 128 + tm * 16 + c16 * 4 + i;
        float e = __expf(acc[tm][tn][i] * scale);
        __bf16 h = (__bf16)e;
        Eb[(size_t)q * SEQ + k] = *(const unsigned short*)&h;
        rs[tm][i] += (float)h;
      }
    }
#pragma unroll
  for (int tm = 0; tm < 8; ++tm)
#pragma unroll
    for (int i = 0; i < 4; ++i) {
      float v = rs[tm][i];
      v += __shfl_xor(v, 1);
      v += __shfl_xor(v, 2);
      v += __shfl_xor(v, 4);
      v += __shfl_xor(v, 8);
      rs[tm][i] = v;
    }
  if (l15 == 0) {
#pragma unroll
    for (int tm = 0; tm < 8; ++tm)
#pragma unroll
      for (int i = 0; i < 4; ++i) {
        int q = m0 + wr * 128 + tm * 16 + c16 * 4 + i;
        atomicAdd(&lr[q], rs[tm][i]);
      }
  }
}

// ---------------------------------------------------------------------------
// PV, phase-split (2 phases/K-tile): 256q x 128d, BK=64, 8 waves (4M x 2N,
// per-wave 64x64), 96 KB LDS, grid 256 = 1 block/CU, conflict-free swizzle.
// ---------------------------------------------------------------------------
__global__ __launch_bounds__(512, 2) void k_pv8(const unsigned short* __restrict__ E_c,
                                                const unsigned short* __restrict__ Vt,
                                                float* __restrict__ O12, int b0) {
  __shared__ __align__(16) unsigned short LA[2][256 * 64];   // E rows: 2 x 32 KB
  __shared__ __align__(16) unsigned short LB[2][128 * 64];   // V rows: 2 x 16 KB
  const int z = blockIdx.z, b = b0 + (z >> 1);
  const int q0 = blockIdx.y * 256, n0 = blockIdx.x * 128;
  const unsigned short* Ae = E_c + (size_t)z * SEQ * SEQ;
  const unsigned short* Bv = Vt + (size_t)b * DHEAD * SEQ;
  float* Ob = O12 + (size_t)z * SEQ * DHEAD;
  const int t = threadIdx.x, w = t >> 6, lane = t & 63;
  const int wr = w >> 1, wc = w & 1;           // wave: 64q x 64d
  const int l15 = lane & 15, c16 = lane >> 4, x7 = l15 & 7;

  f32x4 acc[4][4];
#pragma unroll
  for (int i = 0; i < 4; ++i)
#pragma unroll
    for (int j = 0; j < 4; ++j) acc[i][j] = f32x4{0.f, 0.f, 0.f, 0.f};

  unsigned goffE[4], goffV[2]; int loffE[4], loffV[2];
#pragma unroll
  for (int i = 0; i < 4; ++i) {
    int c = w * 64 + lane + 512 * i;           // 2048 chunks (256 rows x 8)
    int r = c >> 3;
    int sg = (c & 7) ^ (r & 7);
    goffE[i] = (unsigned)((q0 + r) * SEQ + sg * 8);
    loffE[i] = (w * 64 + 512 * i) * 8;
  }
#pragma unroll
  for (int i = 0; i < 2; ++i) {
    int c = w * 64 + lane + 512 * i;           // 1024 chunks (128 rows x 8)
    int r = c >> 3;
    int sg = (c & 7) ^ (r & 7);
    goffV[i] = (unsigned)((n0 + r) * SEQ + sg * 8);
    loffV[i] = (w * 64 + 512 * i) * 8;
  }

  auto STAGE = [&](int buf, int kh) {
#pragma unroll
    for (int i = 0; i < 4; ++i) gld_lds16(Ae + goffE[i] + kh, &LA[buf][loffE[i]]);
#pragma unroll
    for (int i = 0; i < 2; ++i) gld_lds16(Bv + goffV[i] + kh, &LB[buf][loffV[i]]);
  };

#define LDA_P(CB, R, KS) (*(const bf16x8*)&LA[CB][(R) * 64 + ((((KS) * 4 + c16) ^ x7) * 8)])
#define LDB_P(CB, R, KS) (*(const bf16x8*)&LB[CB][(R) * 64 + ((((KS) * 4 + c16) ^ x7) * 8)])

  STAGE(0, 0);
  WAITCNT(0);
  BAR();

  for (int kt = 0; kt < 64; ++kt) {            // K = 4096 = 64 x 64
    const int cb = kt & 1;
    bf16x8 af[4][2], b0f[2][2], b1f[2][2];
    // ---- P0: stage next K-tile; read af(all) + bfr-lo; MFMA n-lo half
    if (kt < 63) STAGE(cb ^ 1, (kt + 1) * 64);
#pragma unroll
    for (int tq = 0; tq < 4; ++tq)
#pragma unroll
      for (int ks = 0; ks < 2; ++ks)
        af[tq][ks] = LDA_P(cb, wr * 64 + tq * 16 + l15, ks);
#pragma unroll
    for (int tn = 0; tn < 2; ++tn)
#pragma unroll
      for (int ks = 0; ks < 2; ++ks)
        b0f[tn][ks] = LDB_P(cb, wc * 64 + tn * 16 + l15, ks);
    BAR(); LGKM0(); SCHED0();
    PRIO1();
#pragma unroll
    for (int tq = 0; tq < 4; ++tq)
#pragma unroll
      for (int tn = 0; tn < 2; ++tn)
#pragma unroll
        for (int ks = 0; ks < 2; ++ks)
          acc[tq][tn] = __builtin_amdgcn_mfma_f32_16x16x32_bf16(
              af[tq][ks], b0f[tn][ks], acc[tq][tn], 0, 0, 0);
    PRIO0();
    BAR();
    // ---- P1: read bfr-hi; MFMA n-hi half; K-tile boundary drain
#pragma unroll
    for (int tn = 0; tn < 2; ++tn)
#pragma unroll
      for (int ks = 0; ks < 2; ++ks)
        b1f[tn][ks] = LDB_P(cb, wc * 64 + (tn + 2) * 16 + l15, ks);
    BAR(); LGKM0(); SCHED0();
    PRIO1();
#pragma unroll
    for (int tq = 0; tq < 4; ++tq)
#pragma unroll
      for (int tn = 0; tn < 2; ++tn)
#pragma unroll
        for (int ks = 0; ks < 2; ++ks)
          acc[tq][tn + 2] = __builtin_amdgcn_mfma_f32_16x16x32_bf16(
              af[tq][ks], b1f[tn][ks], acc[tq][tn + 2], 0, 0, 0);
    PRIO0();
    if (kt < 63) WAITCNT(0);
    BAR();
  }
#undef LDA_P
#undef LDB_P

#pragma unroll
  for (int tq = 0; tq < 4; ++tq)
#pragma unroll
    for (int tn = 0; tn < 4; ++tn) {
      int d = n0 + wc * 64 + tn * 16 + l15;
#pragma unroll
      for (int i = 0; i < 4; ++i) {
        int q = q0 + wr * 64 + tq * 16 + c16 * 4 + i;
        Ob[(size_t)q * DHEAD + d] = acc[tq][tn][i];
      }
    }
}

// Chunk combine: out[b0+rb] = O12[rb*2+0]/l1 - lambda * O12[rb*2+1]/l2
__global__ void k_combine(const float* __restrict__ O12, const float* __restrict__ ls,
                          const float* __restrict__ lam, float* __restrict__ out, int b0) {
  int i = blockIdx.x * blockDim.x + threadIdx.x;
  float lambda = expf(lam[0]) + 0.05f;
  int gq = i >> 7;
  int rb = gq >> 12;
  int q = gq & 4095;
  int dv = i & 127;
  int b = b0 + rb;
  float inv1 = 1.f / ls[(size_t)b * SEQ + q];
  float inv2 = lambda / ls[NTOK + (size_t)b * SEQ + q];
  size_t ai = (size_t)(rb * 2) * (SEQ * 128) + (size_t)q * 128 + dv;
  float4 a = ((const float4*)O12)[ai];
  float4 c = ((const float4*)O12)[ai + SEQ * 128];
  float4 r;
  r.x = a.x * inv1 - c.x * inv2;
  r.y = a.y * inv1 - c.y * inv2;
  r.z = a.z * inv1 - c.z * inv2;
  r.w = a.w * inv1 - c.w * inv2;
  ((float4*)out)[(size_t)(b * SEQ + q) * 128 + dv] = r;
}

// ---------------------------------------------------------------------------
extern "C" void kernel_launch(void* const* d_in, const int* in_sizes, int n_in,
                              void* d_out, int out_size, void* d_ws, size_t ws_size,
                              hipStream_t stream) {
  const float* X   = (const float*)d_in[0];
  const float* Wq  = (const float*)d_in[1];
  const float* bq  = (const float*)d_in[2];
  const float* Wk  = (const float*)d_in[3];
  const float* bk  = (const float*)d_in[4];
  const float* Wv  = (const float*)d_in[5];
  const float* bv  = (const float*)d_in[6];
  const float* lam = (const float*)d_in[7];
  float* out = (float*)d_out;

  char* ws = (char*)d_ws;
  size_t off = 0;
  auto alloc = [&](size_t b) { size_t r = off; off += (b + 255) & ~(size_t)255; return r; };
  unsigned short* Xb  = (unsigned short*)(ws + alloc((size_t)NTOK * EDIM * 2));    // 32 MiB
  unsigned short* Wb  = (unsigned short*)(ws + alloc((size_t)FQKV * EDIM * 2));    // 5 MiB
  float*          bc  = (float*)(ws + alloc((size_t)FQKV * 4));
  unsigned short* QK  = (unsigned short*)(ws + alloc((size_t)NTOK * FQK * 2));     // 64 MiB
  unsigned short* Vt  = (unsigned short*)(ws + alloc((size_t)NB * DHEAD * SEQ * 2)); // 16 MiB
  unsigned short* E_c = (unsigned short*)(ws + alloc((size_t)4 * SEQ * SEQ * 2));  // 128 MiB
  float*          ls  = (float*)(ws + alloc((size_t)2 * NTOK * 4));                // 128 KiB
  float* O12 = (float*)Xb;  // 32 MiB alias; Xb dead after k_v
  // total ws ~245.2 MiB (< 256 MiB)

  k_cvt_x<<<dim3((NTOK * EDIM / 4) / 256), dim3(256), 0, stream>>>(X, Xb);
  k_pack_w<<<dim3((FQKV * EDIM / 4) / 256), dim3(256), 0, stream>>>(Wq, Wk, Wv, Wb);
  k_pack_b<<<dim3(10), dim3(256), 0, stream>>>(bq, bk, bv, bc);
  k_qk<<<dim3(FQK / 128, NTOK / 128), dim3(256), 0, stream>>>(Xb, Wb, bc, QK);
  k_v<<<dim3(SEQ / 128, DHEAD / 128, NB), dim3(256), 0, stream>>>(Xb, Wb, bc, Vt);
  k_zero_f<<<dim3(2 * NTOK / 256), dim3(256), 0, stream>>>(ls);
  for (int b0 = 0; b0 < NB; b0 += 2) {
    k_scores8<<<dim3(SEQ / 256, SEQ / 256, 4), dim3(512), 0, stream>>>(QK, E_c, ls, b0);
    k_pv8<<<dim3(DHEAD / 128, SEQ / 256, 4), dim3(512), 0, stream>>>(E_c, Vt, O12, b0);
    k_combine<<<dim3((2 * SEQ * DHEAD / 4) / 256), dim3(256), 0, stream>>>(O12, ls, lam, out, b0);
  }

  (void)in_sizes; (void)n_in; (void)out_size; (void)ws_size;
}

// Round 10
// 683.988 us; speedup vs baseline: 1.0732x; 1.0732x over previous
//
#include <hip/hip_runtime.h>
#include <cstdint>
#include <cstddef>

// Problem constants
#define NB    4
#define SEQ   4096
#define EDIM  1024
#define DHEAD 512
#define NTOK  (NB * SEQ)     // 16384
#define FQK   2048           // Q and K features only
#define FQKV  2560

typedef __bf16 bf16x8 __attribute__((ext_vector_type(8)));
typedef float  f32x4  __attribute__((ext_vector_type(4)));

#define WAITCNT(VM) asm volatile("s_waitcnt vmcnt(" #VM ") lgkmcnt(0)" ::: "memory")
#define LGKM0()     asm volatile("s_waitcnt lgkmcnt(0)" ::: "memory")
#define SCHED0()    __builtin_amdgcn_sched_barrier(0)   // rule #18: fence MFMA hoisting
#define BAR()       __builtin_amdgcn_s_barrier()
#define PRIO1()     __builtin_amdgcn_s_setprio(1)
#define PRIO0()     __builtin_amdgcn_s_setprio(0)

__device__ __forceinline__ unsigned short f2bf(float f) {
  union { float f; unsigned int u; } v; v.f = f;
  return (unsigned short)((v.u + 0x7fffu + ((v.u >> 16) & 1u)) >> 16);
}

// async global->LDS, 16B per lane; LDS dest wave-uniform base, lane i -> base+i*16.
__device__ __forceinline__ void gld_lds16(const void* g, void* l) {
  __builtin_amdgcn_global_load_lds(
      (const __attribute__((address_space(1))) unsigned int*)g,
      (__attribute__((address_space(3))) unsigned int*)l, 16, 0, 0);
}

// ---------------------------------------------------------------------------
// 2-phase dbuf GEMM-BT core for k_qk / k_v (round-7, verified): 128x128, BK=32.
// ---------------------------------------------------------------------------
template <class Epi>
__device__ __forceinline__ void gemm_bt_core(
    const unsigned short* __restrict__ A, const unsigned short* __restrict__ B,
    int K, int lda, int ldb, int m0, int n0, Epi epi) {
  __shared__ __align__(16) unsigned short As[2][128 * 32];
  __shared__ __align__(16) unsigned short Bs[2][128 * 32];
  const int t = threadIdx.x;
  const int w = t >> 6;
  const int lane = t & 63;
  const int wr = w >> 1, wc = w & 1;
  const int l15 = lane & 15, c16 = lane >> 4, x3 = l15 & 3;

  f32x4 acc[4][4];
#pragma unroll
  for (int i = 0; i < 4; ++i)
#pragma unroll
    for (int j = 0; j < 4; ++j) acc[i][j] = f32x4{0.f, 0.f, 0.f, 0.f};

  const int c0 = w * 128 + lane;
  const int c1 = w * 128 + 64 + lane;
  const int r0 = c0 >> 2, s0 = (c0 & 3) ^ (r0 & 3);
  const int r1 = c1 >> 2, s1 = (c1 & 3) ^ (r1 & 3);
  const int o0 = (w * 128) * 8;
  const int o1 = (w * 128 + 64) * 8;
  const unsigned short* gA0 = A + (size_t)(m0 + r0) * lda + s0 * 8;
  const unsigned short* gA1 = A + (size_t)(m0 + r1) * lda + s1 * 8;
  const unsigned short* gB0 = B + (size_t)(n0 + r0) * ldb + s0 * 8;
  const unsigned short* gB1 = B + (size_t)(n0 + r1) * ldb + s1 * 8;

  auto STAGE = [&](int buf, int kt) {
    gld_lds16(gA0 + kt, &As[buf][o0]);
    gld_lds16(gA1 + kt, &As[buf][o1]);
    gld_lds16(gB0 + kt, &Bs[buf][o0]);
    gld_lds16(gB1 + kt, &Bs[buf][o1]);
  };

  STAGE(0, 0);
  const int NT = K >> 5;
  for (int tt = 0; tt < NT; ++tt) {
    const int cb = tt & 1;
    if (tt + 1 < NT) { STAGE(cb ^ 1, (tt + 1) * 32); WAITCNT(4); }
    else             { WAITCNT(0); }
    BAR();
    PRIO1();
    bf16x8 af[4], bfr[4];
#pragma unroll
    for (int tm = 0; tm < 4; ++tm) {
      int r = wr * 64 + tm * 16 + l15;
      af[tm] = *(const bf16x8*)&As[cb][r * 32 + ((c16 ^ x3) * 8)];
    }
#pragma unroll
    for (int tn = 0; tn < 4; ++tn) {
      int r = wc * 64 + tn * 16 + l15;
      bfr[tn] = *(const bf16x8*)&Bs[cb][r * 32 + ((c16 ^ x3) * 8)];
    }
#pragma unroll
    for (int tm = 0; tm < 4; ++tm)
#pragma unroll
      for (int tn = 0; tn < 4; ++tn)
        acc[tm][tn] = __builtin_amdgcn_mfma_f32_16x16x32_bf16(
            af[tm], bfr[tn], acc[tm][tn], 0, 0, 0);
    PRIO0();
    BAR();
  }
  epi(acc, wr, wc, lane);
}

// ---------------------------------------------------------------------------
// Utility kernels
// ---------------------------------------------------------------------------
__global__ void k_cvt_x(const float* __restrict__ X, unsigned short* __restrict__ Xb) {
  int i = blockIdx.x * blockDim.x + threadIdx.x;
  float4 v = ((const float4*)X)[i];
  ushort4 o;
  o.x = f2bf(v.x); o.y = f2bf(v.y); o.z = f2bf(v.z); o.w = f2bf(v.w);
  ((ushort4*)Xb)[i] = o;
}

__global__ void k_pack_w(const float* __restrict__ Wq, const float* __restrict__ Wk,
                         const float* __restrict__ Wv, unsigned short* __restrict__ Wb) {
  int i = blockIdx.x * blockDim.x + threadIdx.x;
  int idx = i * 4;
  int f = idx >> 10, e = idx & 1023;
  const float* src = (f < 1024) ? (Wq + (size_t)f * 1024)
                   : (f < 2048) ? (Wk + (size_t)(f - 1024) * 1024)
                                : (Wv + (size_t)(f - 2048) * 1024);
  float4 v = *(const float4*)(src + e);
  ushort4 o;
  o.x = f2bf(v.x); o.y = f2bf(v.y); o.z = f2bf(v.z); o.w = f2bf(v.w);
  ((ushort4*)Wb)[i] = o;
}

__global__ void k_pack_b(const float* __restrict__ bq, const float* __restrict__ bk,
                         const float* __restrict__ bv, float* __restrict__ bc) {
  int f = blockIdx.x * blockDim.x + threadIdx.x;
  if (f < FQKV)
    bc[f] = (f < 1024) ? bq[f] : (f < 2048) ? bk[f - 1024] : bv[f - 2048];
}

__global__ void k_zero_f(float* __restrict__ p) {
  int i = blockIdx.x * blockDim.x + threadIdx.x;
  p[i] = 0.f;
}

// ---------------------------------------------------------------------------
// QK / V projection GEMMs (round-7, verified)
// ---------------------------------------------------------------------------
__global__ __launch_bounds__(256) void k_qk(const unsigned short* __restrict__ Xb,
                                            const unsigned short* __restrict__ Wb,
                                            const float* __restrict__ bc,
                                            unsigned short* __restrict__ QK) {
  const int m0 = blockIdx.y * 128, n0 = blockIdx.x * 128;
  gemm_bt_core(Xb, Wb, EDIM, EDIM, EDIM, m0, n0,
    [&](f32x4 (&acc)[4][4], int wr, int wc, int lane) {
#pragma unroll
      for (int tm = 0; tm < 4; ++tm)
#pragma unroll
        for (int tn = 0; tn < 4; ++tn) {
          int kc = n0 + wc * 64 + tn * 16 + (lane & 15);
          float bias = bc[kc];
#pragma unroll
          for (int i = 0; i < 4; ++i) {
            int q = m0 + wr * 64 + tm * 16 + (lane >> 4) * 4 + i;
            __bf16 h = (__bf16)(acc[tm][tn][i] + bias);
            QK[(size_t)q * FQK + kc] = *(const unsigned short*)&h;
          }
        }
    });
}

__global__ __launch_bounds__(256) void k_v(const unsigned short* __restrict__ Xb,
                                           const unsigned short* __restrict__ Wb,
                                           const float* __restrict__ bc,
                                           unsigned short* __restrict__ Vt) {
  const int b = blockIdx.z;
  const int m0 = blockIdx.y * 128;  // d tile
  const int n0 = blockIdx.x * 128;  // s tile
  const unsigned short* A = Wb + (size_t)2048 * EDIM;
  const unsigned short* B = Xb + (size_t)b * SEQ * EDIM;
  unsigned short* Vb = Vt + (size_t)b * DHEAD * SEQ;
  gemm_bt_core(A, B, EDIM, EDIM, EDIM, m0, n0,
    [&](f32x4 (&acc)[4][4], int wr, int wc, int lane) {
#pragma unroll
      for (int tm = 0; tm < 4; ++tm)
#pragma unroll
        for (int tn = 0; tn < 4; ++tn) {
          int s = n0 + wc * 64 + tn * 16 + (lane & 15);
#pragma unroll
          for (int i = 0; i < 4; ++i) {
            int d = m0 + wr * 64 + tm * 16 + (lane >> 4) * 4 + i;
            __bf16 h = (__bf16)(acc[tm][tn][i] + bc[2048 + d]);
            Vb[(size_t)d * SEQ + s] = *(const unsigned short*)&h;
          }
        }
    });
}

// ---------------------------------------------------------------------------
// Scores, derived-waits 4-phase schedule: 256q x 256k, BK=64, 8 waves (2M x
// 4N, per-wave 128x64), 128 KB LDS, conflict-free 8-slot swizzle (r4: cnt=0).
// Staging of tile t+1 is SPREAD across tile t's phases (2 gld/thread/phase):
//   P0: B-g01  P1: B-g23  P2: A-g02  P3: A-g13
// (A groups {0,2} = rows each wave's m-lo frags read; B all groups by P0.)
// Counted waits (per-wave ledger, never drain mid-loop):
//   end-P1 vmcnt(4): retires A-g13(t) before P2's ds_read
//   end-P3 vmcnt(2): retires B-all + A-g02(t+1) before next P0/P1
// ---------------------------------------------------------------------------
__global__ __launch_bounds__(512, 2) void k_scores8(const unsigned short* __restrict__ QK,
                                                    unsigned short* __restrict__ E_c,
                                                    float* __restrict__ ls, int b0) {
  __shared__ __align__(16) unsigned short LA[2][256 * 64];   // 2 x 32 KB
  __shared__ __align__(16) unsigned short LB[2][256 * 64];   // 2 x 32 KB
  const int z = blockIdx.z, rb = z >> 1, which = z & 1, b = b0 + rb;
  const int m0 = blockIdx.y * 256, n0 = blockIdx.x * 256;
  const unsigned short* Aq = QK + (size_t)b * SEQ * FQK + which * 512;
  const unsigned short* Bk = Aq + 1024;
  unsigned short* Eb = E_c + (size_t)z * SEQ * SEQ;
  float* lr = ls + (size_t)which * NTOK + (size_t)b * SEQ;
  const int t = threadIdx.x, w = t >> 6, lane = t & 63;
  const int wr = w >> 2, wc = w & 3;           // wave: 128q x 64k
  const int l15 = lane & 15, c16 = lane >> 4, x7 = l15 & 7;

  f32x4 acc[8][4];
#pragma unroll
  for (int i = 0; i < 8; ++i)
#pragma unroll
    for (int j = 0; j < 4; ++j) acc[i][j] = f32x4{0.f, 0.f, 0.f, 0.f};

  // Group i covers rows [64i, 64i+64) (this wave's slice: 64i + w*8 .. +8).
  unsigned goffA[4], goffB[4]; int loff[4];
#pragma unroll
  for (int i = 0; i < 4; ++i) {
    int c = w * 64 + lane + 512 * i;
    int r = c >> 3;
    int sg = (c & 7) ^ (r & 7);
    goffA[i] = (unsigned)((m0 + r) * FQK + sg * 8);
    goffB[i] = (unsigned)((n0 + r) * FQK + sg * 8);
    loff[i] = (w * 64 + 512 * i) * 8;
  }

  auto stgA = [&](int buf, int i, int kh) { gld_lds16(Aq + goffA[i] + kh, &LA[buf][loff[i]]); };
  auto stgB = [&](int buf, int i, int kh) { gld_lds16(Bk + goffB[i] + kh, &LB[buf][loff[i]]); };

#define LDA_S(CB, R, KS) (*(const bf16x8*)&LA[CB][(R) * 64 + ((((KS) * 4 + c16) ^ x7) * 8)])
#define LDB_S(CB, R, KS) (*(const bf16x8*)&LB[CB][(R) * 64 + ((((KS) * 4 + c16) ^ x7) * 8)])

  // Prologue: stage tile 0 in consumption-priority order; retire all but A-g13.
  stgB(0, 0, 0); stgB(0, 1, 0); stgB(0, 2, 0); stgB(0, 3, 0);
  stgA(0, 0, 0); stgA(0, 2, 0); stgA(0, 1, 0); stgA(0, 3, 0);
  WAITCNT(2);
  BAR();

  for (int kt = 0; kt < 8; ++kt) {            // K = 512 = 8 x 64
    const int cb = kt & 1, nb = cb ^ 1;
    const int kh = (kt + 1) * 64;
    bf16x8 af[4][2], b0f[2][2], b1f[2][2];

    // ---- P0: ds_read af-lo + b0f; stage B-g01(t+1); MFMA Q(m-lo, n-lo)
#pragma unroll
    for (int tq = 0; tq < 4; ++tq)
#pragma unroll
      for (int ks = 0; ks < 2; ++ks)
        af[tq][ks] = LDA_S(cb, wr * 128 + tq * 16 + l15, ks);
#pragma unroll
    for (int tn = 0; tn < 2; ++tn)
#pragma unroll
      for (int ks = 0; ks < 2; ++ks)
        b0f[tn][ks] = LDB_S(cb, wc * 64 + tn * 16 + l15, ks);
    if (kt < 7) { stgB(nb, 0, kh); stgB(nb, 1, kh); }
    BAR(); LGKM0(); SCHED0();
    PRIO1();
#pragma unroll
    for (int tq = 0; tq < 4; ++tq)
#pragma unroll
      for (int tn = 0; tn < 2; ++tn)
#pragma unroll
        for (int ks = 0; ks < 2; ++ks)
          acc[tq][tn] = __builtin_amdgcn_mfma_f32_16x16x32_bf16(
              af[tq][ks], b0f[tn][ks], acc[tq][tn], 0, 0, 0);
    PRIO0();
    BAR();

    // ---- P1: ds_read b1f; stage B-g23(t+1); MFMA Q(m-lo, n-hi); vmcnt(4)
#pragma unroll
    for (int tn = 0; tn < 2; ++tn)
#pragma unroll
      for (int ks = 0; ks < 2; ++ks)
        b1f[tn][ks] = LDB_S(cb, wc * 64 + (tn + 2) * 16 + l15, ks);
    if (kt < 7) { stgB(nb, 2, kh); stgB(nb, 3, kh); }
    BAR(); LGKM0(); SCHED0();
    PRIO1();
#pragma unroll
    for (int tq = 0; tq < 4; ++tq)
#pragma unroll
      for (int tn = 0; tn < 2; ++tn)
#pragma unroll
        for (int ks = 0; ks < 2; ++ks)
          acc[tq][tn + 2] = __builtin_amdgcn_mfma_f32_16x16x32_bf16(
              af[tq][ks], b1f[tn][ks], acc[tq][tn + 2], 0, 0, 0);
    PRIO0();
    if (kt < 7) WAITCNT(4); else WAITCNT(0);   // retire A-g13(t) for P2's read
    BAR();

    // ---- P2: ds_read af-hi; stage A-g02(t+1); MFMA Q(m-hi, n-hi)
#pragma unroll
    for (int tq = 0; tq < 4; ++tq)
#pragma unroll
      for (int ks = 0; ks < 2; ++ks)
        af[tq][ks] = LDA_S(cb, wr * 128 + 64 + tq * 16 + l15, ks);
    if (kt < 7) { stgA(nb, 0, kh); stgA(nb, 2, kh); }
    BAR(); LGKM0(); SCHED0();
    PRIO1();
#pragma unroll
    for (int tq = 0; tq < 4; ++tq)
#pragma unroll
      for (int tn = 0; tn < 2; ++tn)
#pragma unroll
        for (int ks = 0; ks < 2; ++ks)
          acc[4 + tq][tn + 2] = __builtin_amdgcn_mfma_f32_16x16x32_bf16(
              af[tq][ks], b1f[tn][ks], acc[4 + tq][tn + 2], 0, 0, 0);
    PRIO0();
    BAR();

    // ---- P3: stage A-g13(t+1); MFMA Q(m-hi, n-lo) (regs ready); vmcnt(2)
    if (kt < 7) { stgA(nb, 1, kh); stgA(nb, 3, kh); }
    PRIO1();
#pragma unroll
    for (int tq = 0; tq < 4; ++tq)
#pragma unroll
      for (int tn = 0; tn < 2; ++tn)
#pragma unroll
        for (int ks = 0; ks < 2; ++ks)
          acc[4 + tq][tn] = __builtin_amdgcn_mfma_f32_16x16x32_bf16(
              af[tq][ks], b0f[tn][ks], acc[4 + tq][tn], 0, 0, 0);
    PRIO0();
    if (kt < 7) WAITCNT(2);                    // B-all + A-g02(t+1) landed
    BAR();
  }
#undef LDA_S
#undef LDB_S

  // Epilogue: exp + native bf16 cast + direct stores + row sums.
  const float scale = 0.04419417382415922f;  // 1/sqrt(512)
  float rs[8][4];
#pragma unroll
  for (int tm = 0; tm < 8; ++tm)
#pragma unroll
    for (int i = 0; i < 4; ++i) rs[tm][i] = 0.f;
#pragma unroll
  for (int tm = 0; tm < 8; ++tm)
#pragma unroll
    for (int tn = 0; tn < 4; ++tn) {
      int k = n0 + wc * 64 + tn * 16 + l15;
#pragma unroll
      for (int i = 0; i < 4; ++i) {
        int q = m0 + wr * 128 + tm * 16 + c16 * 4 + i;
        float e = __expf(acc[tm][tn][i] * scale);
        __bf16 h = (__bf16)e;
        Eb[(size_t)q * SEQ + k] = *(const unsigned short*)&h;
        rs[tm][i] += (float)h;
      }
    }
#pragma unroll
  for (int tm = 0; tm < 8; ++tm)
#pragma unroll
    for (int i = 0; i < 4; ++i) {
      float v = rs[tm][i];
      v += __shfl_xor(v, 1);
      v += __shfl_xor(v, 2);
      v += __shfl_xor(v, 4);
      v += __shfl_xor(v, 8);
      rs[tm][i] = v;
    }
  if (l15 == 0) {
#pragma unroll
    for (int tm = 0; tm < 8; ++tm)
#pragma unroll
      for (int i = 0; i < 4; ++i) {
        int q = m0 + wr * 128 + tm * 16 + c16 * 4 + i;
        atomicAdd(&lr[q], rs[tm][i]);
      }
  }
}

// ---------------------------------------------------------------------------
// PV: round-7 monolithic counted version (best measured): 256q x 128d, BK=64,
// 8 waves (4M x 2N each 64x64), 96 KB LDS, grid 256 = 1 block/CU.
// ---------------------------------------------------------------------------
__global__ __launch_bounds__(512, 2) void k_pv8(const unsigned short* __restrict__ E_c,
                                                const unsigned short* __restrict__ Vt,
                                                float* __restrict__ O12, int b0) {
  __shared__ __align__(16) unsigned short LA[2][256 * 64];   // E rows: 2 x 32 KB
  __shared__ __align__(16) unsigned short LB[2][128 * 64];   // V rows: 2 x 16 KB
  const int z = blockIdx.z, b = b0 + (z >> 1);
  const int q0 = blockIdx.y * 256, n0 = blockIdx.x * 128;
  const unsigned short* Ae = E_c + (size_t)z * SEQ * SEQ;    // rows q, stride SEQ
  const unsigned short* Bv = Vt + (size_t)b * DHEAD * SEQ;   // rows d, stride SEQ
  float* Ob = O12 + (size_t)z * SEQ * DHEAD;
  const int t = threadIdx.x, w = t >> 6, lane = t & 63;
  const int wr = w >> 1, wc = w & 1;           // wave: 64q x 64d
  const int l15 = lane & 15, c16 = lane >> 4, x7 = l15 & 7;

  f32x4 acc[4][4];
#pragma unroll
  for (int i = 0; i < 4; ++i)
#pragma unroll
    for (int j = 0; j < 4; ++j) acc[i][j] = f32x4{0.f, 0.f, 0.f, 0.f};

  unsigned goffE[4], goffV[2]; int loffE[4], loffV[2];
#pragma unroll
  for (int i = 0; i < 4; ++i) {
    int c = w * 64 + lane + 512 * i;           // 2048 chunks (256 rows x 8)
    int r = c >> 3;
    int sg = (c & 7) ^ (r & 7);
    goffE[i] = (unsigned)((q0 + r) * SEQ + sg * 8);
    loffE[i] = (w * 64 + 512 * i) * 8;
  }
#pragma unroll
  for (int i = 0; i < 2; ++i) {
    int c = w * 64 + lane + 512 * i;           // 1024 chunks (128 rows x 8)
    int r = c >> 3;
    int sg = (c & 7) ^ (r & 7);
    goffV[i] = (unsigned)((n0 + r) * SEQ + sg * 8);
    loffV[i] = (w * 64 + 512 * i) * 8;
  }

  auto STAGE = [&](int buf, int kh) {
#pragma unroll
    for (int i = 0; i < 4; ++i) gld_lds16(Ae + goffE[i] + kh, &LA[buf][loffE[i]]);
#pragma unroll
    for (int i = 0; i < 2; ++i) gld_lds16(Bv + goffV[i] + kh, &LB[buf][loffV[i]]);
  };

  STAGE(0, 0);
  for (int kt = 0; kt < 64; ++kt) {            // K = 4096 = 64 x 64
    const int cb = kt & 1;
    if (kt < 63) { STAGE(cb ^ 1, (kt + 1) * 64); WAITCNT(6); }
    else         { WAITCNT(0); }
    BAR();
    PRIO1();
    bf16x8 af[4][2], bfr[4][2];
#pragma unroll
    for (int tn = 0; tn < 4; ++tn)
#pragma unroll
      for (int ks = 0; ks < 2; ++ks)
        bfr[tn][ks] = *(const bf16x8*)
            &LB[cb][(wc * 64 + tn * 16 + l15) * 64 + (((ks * 4 + c16) ^ x7) * 8)];
#pragma unroll
    for (int tq = 0; tq < 4; ++tq)
#pragma unroll
      for (int ks = 0; ks < 2; ++ks)
        af[tq][ks] = *(const bf16x8*)
            &LA[cb][(wr * 64 + tq * 16 + l15) * 64 + (((ks * 4 + c16) ^ x7) * 8)];
#pragma unroll
    for (int tq = 0; tq < 4; ++tq)
#pragma unroll
      for (int tn = 0; tn < 4; ++tn)
#pragma unroll
        for (int ks = 0; ks < 2; ++ks)
          acc[tq][tn] = __builtin_amdgcn_mfma_f32_16x16x32_bf16(
              af[tq][ks], bfr[tn][ks], acc[tq][tn], 0, 0, 0);
    PRIO0();
    BAR();
  }

#pragma unroll
  for (int tq = 0; tq < 4; ++tq)
#pragma unroll
    for (int tn = 0; tn < 4; ++tn) {
      int d = n0 + wc * 64 + tn * 16 + l15;
#pragma unroll
      for (int i = 0; i < 4; ++i) {
        int q = q0 + wr * 64 + tq * 16 + c16 * 4 + i;
        Ob[(size_t)q * DHEAD + d] = acc[tq][tn][i];
      }
    }
}

// Chunk combine: out[b0+rb] = O12[rb*2+0]/l1 - lambda * O12[rb*2+1]/l2
__global__ void k_combine(const float* __restrict__ O12, const float* __restrict__ ls,
                          const float* __restrict__ lam, float* __restrict__ out, int b0) {
  int i = blockIdx.x * blockDim.x + threadIdx.x;
  float lambda = expf(lam[0]) + 0.05f;
  int gq = i >> 7;
  int rb = gq >> 12;
  int q = gq & 4095;
  int dv = i & 127;
  int b = b0 + rb;
  float inv1 = 1.f / ls[(size_t)b * SEQ + q];
  float inv2 = lambda / ls[NTOK + (size_t)b * SEQ + q];
  size_t ai = (size_t)(rb * 2) * (SEQ * 128) + (size_t)q * 128 + dv;
  float4 a = ((const float4*)O12)[ai];
  float4 c = ((const float4*)O12)[ai + SEQ * 128];
  float4 r;
  r.x = a.x * inv1 - c.x * inv2;
  r.y = a.y * inv1 - c.y * inv2;
  r.z = a.z * inv1 - c.z * inv2;
  r.w = a.w * inv1 - c.w * inv2;
  ((float4*)out)[(size_t)(b * SEQ + q) * 128 + dv] = r;
}

// ---------------------------------------------------------------------------
extern "C" void kernel_launch(void* const* d_in, const int* in_sizes, int n_in,
                              void* d_out, int out_size, void* d_ws, size_t ws_size,
                              hipStream_t stream) {
  const float* X   = (const float*)d_in[0];
  const float* Wq  = (const float*)d_in[1];
  const float* bq  = (const float*)d_in[2];
  const float* Wk  = (const float*)d_in[3];
  const float* bk  = (const float*)d_in[4];
  const float* Wv  = (const float*)d_in[5];
  const float* bv  = (const float*)d_in[6];
  const float* lam = (const float*)d_in[7];
  float* out = (float*)d_out;

  char* ws = (char*)d_ws;
  size_t off = 0;
  auto alloc = [&](size_t b) { size_t r = off; off += (b + 255) & ~(size_t)255; return r; };
  unsigned short* Xb  = (unsigned short*)(ws + alloc((size_t)NTOK * EDIM * 2));    // 32 MiB
  unsigned short* Wb  = (unsigned short*)(ws + alloc((size_t)FQKV * EDIM * 2));    // 5 MiB
  float*          bc  = (float*)(ws + alloc((size_t)FQKV * 4));
  unsigned short* QK  = (unsigned short*)(ws + alloc((size_t)NTOK * FQK * 2));     // 64 MiB
  unsigned short* Vt  = (unsigned short*)(ws + alloc((size_t)NB * DHEAD * SEQ * 2)); // 16 MiB
  unsigned short* E_c = (unsigned short*)(ws + alloc((size_t)4 * SEQ * SEQ * 2));  // 128 MiB
  float*          ls  = (float*)(ws + alloc((size_t)2 * NTOK * 4));                // 128 KiB
  float* O12 = (float*)Xb;  // 32 MiB alias; Xb dead after k_v
  // total ws ~245.2 MiB (< 256 MiB)

  k_cvt_x<<<dim3((NTOK * EDIM / 4) / 256), dim3(256), 0, stream>>>(X, Xb);
  k_pack_w<<<dim3((FQKV * EDIM / 4) / 256), dim3(256), 0, stream>>>(Wq, Wk, Wv, Wb);
  k_pack_b<<<dim3(10), dim3(256), 0, stream>>>(bq, bk, bv, bc);
  k_qk<<<dim3(FQK / 128, NTOK / 128), dim3(256), 0, stream>>>(Xb, Wb, bc, QK);
  k_v<<<dim3(SEQ / 128, DHEAD / 128, NB), dim3(256), 0, stream>>>(Xb, Wb, bc, Vt);
  k_zero_f<<<dim3(2 * NTOK / 256), dim3(256), 0, stream>>>(ls);
  for (int b0 = 0; b0 < NB; b0 += 2) {
    k_scores8<<<dim3(SEQ / 256, SEQ / 256, 4), dim3(512), 0, stream>>>(QK, E_c, ls, b0);
    k_pv8<<<dim3(DHEAD / 128, SEQ / 256, 4), dim3(512), 0, stream>>>(E_c, Vt, O12, b0);
    k_combine<<<dim3((2 * SEQ * DHEAD / 4) / 256), dim3(256), 0, stream>>>(O12, ls, lam, out, b0);
  }

  (void)in_sizes; (void)n_in; (void)out_size; (void)ws_size;
}